// Round 2
// baseline (422.398 us; speedup 1.0000x reference)
//
#include <hip/hip_runtime.h>
#include <hip/hip_bf16.h>
#include <math.h>

#define Bb 2
#define Ss 2048
#define Ee 1024
#define Hh 16
#define HDd 64
#define NEG_INF_F -1000000000.0f

typedef __attribute__((ext_vector_type(8))) short bfrag;     // 8 bf16
typedef __attribute__((ext_vector_type(4))) float ffrag;     // 16x16 C/D
typedef __attribute__((ext_vector_type(16))) float ffrag16;  // 32x32 C/D
typedef __attribute__((ext_vector_type(8))) unsigned short us8;

#define C1F 0.1803368801f  /* 0.125 * log2(e) — folded into Q at gemm_qkv */

// ---- bf16 helpers ----------------------------------------------------------
__device__ __forceinline__ unsigned short f2bf(float x) {
  unsigned u = __float_as_uint(x);
  u += 0x7fffu + ((u >> 16) & 1u);
  return (unsigned short)(u >> 16);
}
__device__ __forceinline__ float bf2f(unsigned short h) {
  return __uint_as_float(((unsigned)h) << 16);
}

__device__ __forceinline__ void async_copy16(void* lds, const void* g) {
  __builtin_amdgcn_global_load_lds(
      (const __attribute__((address_space(1))) unsigned int*)g,
      (__attribute__((address_space(3))) unsigned int*)lds, 16, 0, 0);
}

// ---------------------------------------------------------------------------
// Fused split pass: x (4M) -> hi only; Wqkv (3M), Wout (1M) -> hi/lo.
// ---------------------------------------------------------------------------
__global__ __launch_bounds__(256) void split_all(
    const float* __restrict__ x, unsigned short* __restrict__ xh,
    const float* __restrict__ wq, unsigned short* __restrict__ wqh,
    unsigned short* __restrict__ wql,
    const float* __restrict__ wo, unsigned short* __restrict__ woh,
    unsigned short* __restrict__ wol) {
  int bid = blockIdx.x;
  const float* in;
  unsigned short *hi, *lo;
  if (bid < 4096) { in = x; hi = xh; lo = nullptr; }
  else if (bid < 7168) { bid -= 4096; in = wq; hi = wqh; lo = wql; }
  else { bid -= 7168; in = wo; hi = woh; lo = wol; }
  const int idx = (bid * 256 + threadIdx.x) * 4;
  const float4 v = *(const float4*)(in + idx);
  unsigned short h0 = f2bf(v.x), h1 = f2bf(v.y), h2 = f2bf(v.z), h3 = f2bf(v.w);
  ushort4 hv = {h0, h1, h2, h3};
  *(ushort4*)(hi + idx) = hv;
  if (lo) {
    ushort4 lv = {f2bf(v.x - bf2f(h0)), f2bf(v.y - bf2f(h1)),
                  f2bf(v.z - bf2f(h2)), f2bf(v.w - bf2f(h3))};
    *(ushort4*)(lo + idx) = lv;
  }
}

// ---------------------------------------------------------------------------
// LDS slot map (rows of 32 bf16 = 4 x 16B chunks):
// slot(row,q) = (row>>1)*8 + ((((row&1)*4)|q) ^ ((row>>1)&7)).
// ---------------------------------------------------------------------------
__device__ __forceinline__ int gemm_slot(int row, int q) {
  return (row >> 1) * 8 + ((((row & 1) * 4) | q) ^ ((row >> 1) & 7));
}
__device__ __forceinline__ int slot_src_off(int slot, int ld) {
  const int dr = slot >> 3;
  const int idx8 = (slot & 7) ^ (dr & 7);
  const int row = dr * 2 + (idx8 >> 2);
  const int q = idx8 & 3;
  return row * ld + q * 8;
}

// ---------------------------------------------------------------------------
// QKV GEMM, 32x32x16 core: C = xh * (Wh + Wl)^T + bias (2 MFMAs/product).
// 128x128 tile. Epilogue (all single bf16): Q pre-scaled by C1F -> [bh][s][64];
// K -> [bh][s][64]; V^T -> [bh][d][s].
// ---------------------------------------------------------------------------
__global__ __launch_bounds__(256) void gemm_qkv(
    const unsigned short* __restrict__ Ah,
    const unsigned short* __restrict__ Bh, const unsigned short* __restrict__ Bl,
    const float* __restrict__ bias,
    unsigned short* __restrict__ q_h, unsigned short* __restrict__ k_h,
    unsigned short* __restrict__ vt_h) {
  __shared__ unsigned short sm[3 * 4096];
  const int tid = threadIdx.x;
  const int lane = tid & 63;
  const int w = tid >> 6;
  const int wm = w >> 1;
  const int wn = w & 1;
  const int l31 = lane & 31;
  const int e = lane >> 5;
  const int m0 = blockIdx.x * 128;
  const int n0 = blockIdx.y * 128;

  int coff[2], ldsb[2];
#pragma unroll
  for (int u = 0; u < 2; ++u) {
    const int slot = w * 128 + u * 64 + lane;
    coff[u] = slot_src_off(slot, 1024);
    ldsb[u] = (w * 128 + u * 64) * 8;
  }
  const unsigned short* srcs[3] = {
      Ah + (size_t)m0 * 1024, Bh + (size_t)n0 * 1024, Bl + (size_t)n0 * 1024};

  ffrag16 acc[2][2];
#pragma unroll
  for (int i = 0; i < 2; ++i)
#pragma unroll
    for (int j = 0; j < 2; ++j) acc[i][j] = (ffrag16)0.f;

  int ca[2][2], cb[2][2];
#pragma unroll
  for (int t = 0; t < 2; ++t)
#pragma unroll
    for (int h2 = 0; h2 < 2; ++h2) {
      ca[t][h2] = gemm_slot(wm * 64 + t * 32 + l31, h2 * 2 + e) * 8;
      cb[t][h2] = gemm_slot(wn * 64 + t * 32 + l31, h2 * 2 + e) * 8;
    }

  for (int k0 = 0; k0 < 1024; k0 += 32) {
    __syncthreads();
#pragma unroll
    for (int t = 0; t < 3; ++t)
#pragma unroll
      for (int u = 0; u < 2; ++u)
        async_copy16(&sm[t * 4096 + ldsb[u]], srcs[t] + coff[u] + k0);
    __syncthreads();

    bfrag ah[2][2], bhf[2][2], blf[2][2];
#pragma unroll
    for (int t = 0; t < 2; ++t)
#pragma unroll
      for (int h2 = 0; h2 < 2; ++h2) {
        ah[t][h2] = *(const bfrag*)&sm[0 * 4096 + ca[t][h2]];
        bhf[t][h2] = *(const bfrag*)&sm[1 * 4096 + cb[t][h2]];
        blf[t][h2] = *(const bfrag*)&sm[2 * 4096 + cb[t][h2]];
      }
#pragma unroll
    for (int mt = 0; mt < 2; ++mt)
#pragma unroll
      for (int nt = 0; nt < 2; ++nt)
#pragma unroll
        for (int h2 = 0; h2 < 2; ++h2) {
          acc[mt][nt] = __builtin_amdgcn_mfma_f32_32x32x16_bf16(
              ah[mt][h2], bhf[nt][h2], acc[mt][nt], 0, 0, 0);
          acc[mt][nt] = __builtin_amdgcn_mfma_f32_32x32x16_bf16(
              ah[mt][h2], blf[nt][h2], acc[mt][nt], 0, 0, 0);
        }
  }

#pragma unroll
  for (int nt = 0; nt < 2; ++nt) {
    const int n = n0 + wn * 64 + nt * 32 + l31;
    const float bv = bias[n];
    const int h = n / 192;
    const int c = n - h * 192;
    const int d = c & 63;
#pragma unroll
    for (int mt = 0; mt < 2; ++mt) {
      if (c >= 128) {
#pragma unroll
        for (int g = 0; g < 4; ++g) {
          const int m = m0 + wm * 64 + mt * 32 + g * 8 + e * 4;
          const int bidx = m >> 11;
          const int s = m & 2047;
          ushort4 hv4;
          unsigned short* ph = (unsigned short*)&hv4;
#pragma unroll
          for (int r = 0; r < 4; ++r)
            ph[r] = f2bf(acc[mt][nt][g * 4 + r] + bv);
          const size_t off =
              (size_t)(bidx * 16 + h) * (64 * 2048) + (size_t)d * 2048 + s;
          *(ushort4*)(vt_h + off) = hv4;
        }
      } else {
        const float scale = (c < 64) ? C1F : 1.0f;
        unsigned short* dh = (c < 64) ? q_h : k_h;
#pragma unroll
        for (int g = 0; g < 4; ++g)
#pragma unroll
          for (int r = 0; r < 4; ++r) {
            const int m = m0 + wm * 64 + mt * 32 + g * 8 + e * 4 + r;
            const int bidx = m >> 11;
            const int s = m & 2047;
            const size_t off =
                (size_t)(bidx * 16 + h) * (2048 * 64) + (size_t)s * 64 + d;
            dh[off] = f2bf((acc[mt][nt][g * 4 + r] + bv) * scale);
          }
      }
    }
  }
}

// ---------------------------------------------------------------------------
// Out-proj GEMM: A = vals single bf16, B = Wout hi/lo (2 MFMAs/product).
// 128x64 tile, 512 blocks. Writes fp32+bias directly to out.
// ---------------------------------------------------------------------------
__global__ __launch_bounds__(256) void gemm_out2(
    const unsigned short* __restrict__ A,
    const unsigned short* __restrict__ Bh, const unsigned short* __restrict__ Bl,
    const float* __restrict__ bias, float* __restrict__ out) {
  __shared__ unsigned short sm[8192];
  const int tid = threadIdx.x;
  const int lane = tid & 63;
  const int w = tid >> 6;
  const int wm = w >> 1;
  const int wn = w & 1;
  const int l31 = lane & 31;
  const int e = lane >> 5;
  const int m0 = blockIdx.x * 128;
  const int n0 = blockIdx.y * 64;

  int acoff[2], aldsb[2];
#pragma unroll
  for (int u = 0; u < 2; ++u) {
    const int slot = w * 128 + u * 64 + lane;
    acoff[u] = slot_src_off(slot, 1024);
    aldsb[u] = (w * 128 + u * 64) * 8;
  }
  const int bslot = w * 64 + lane;
  const int bcoff = slot_src_off(bslot, 1024);
  const int bldsb = bslot * 8;

  const unsigned short* Ap  = A + (size_t)m0 * 1024;
  const unsigned short* Bph = Bh + (size_t)n0 * 1024;
  const unsigned short* Bpl = Bl + (size_t)n0 * 1024;

  ffrag16 acc[2];
  acc[0] = (ffrag16)0.f;
  acc[1] = (ffrag16)0.f;

  int ca[2][2], cb[2];
#pragma unroll
  for (int t = 0; t < 2; ++t)
#pragma unroll
    for (int h2 = 0; h2 < 2; ++h2)
      ca[t][h2] = gemm_slot(wm * 64 + t * 32 + l31, h2 * 2 + e) * 8;
#pragma unroll
  for (int h2 = 0; h2 < 2; ++h2)
    cb[h2] = gemm_slot(wn * 32 + l31, h2 * 2 + e) * 8;

  for (int k0 = 0; k0 < 1024; k0 += 32) {
    __syncthreads();
#pragma unroll
    for (int u = 0; u < 2; ++u)
      async_copy16(&sm[0 + aldsb[u]], Ap + acoff[u] + k0);
    async_copy16(&sm[4096 + bldsb], Bph + bcoff + k0);
    async_copy16(&sm[6144 + bldsb], Bpl + bcoff + k0);
    __syncthreads();

    bfrag ah[2][2], bhf[2], blf[2];
#pragma unroll
    for (int t = 0; t < 2; ++t)
#pragma unroll
      for (int h2 = 0; h2 < 2; ++h2)
        ah[t][h2] = *(const bfrag*)&sm[0 + ca[t][h2]];
#pragma unroll
    for (int h2 = 0; h2 < 2; ++h2) {
      bhf[h2] = *(const bfrag*)&sm[4096 + cb[h2]];
      blf[h2] = *(const bfrag*)&sm[6144 + cb[h2]];
    }
#pragma unroll
    for (int mt = 0; mt < 2; ++mt)
#pragma unroll
      for (int h2 = 0; h2 < 2; ++h2) {
        acc[mt] = __builtin_amdgcn_mfma_f32_32x32x16_bf16(
            ah[mt][h2], bhf[h2], acc[mt], 0, 0, 0);
        acc[mt] = __builtin_amdgcn_mfma_f32_32x32x16_bf16(
            ah[mt][h2], blf[h2], acc[mt], 0, 0, 0);
      }
  }

  const int n = n0 + wn * 32 + l31;
  const float bv = bias[n];
#pragma unroll
  for (int mt = 0; mt < 2; ++mt)
#pragma unroll
    for (int g = 0; g < 4; ++g)
#pragma unroll
      for (int r = 0; r < 4; ++r) {
        const int m = m0 + wm * 64 + mt * 32 + g * 8 + e * 4 + r;
        out[(size_t)m * 1024 + n] = acc[mt][g * 4 + r] + bv;
      }
}

// ---------------------------------------------------------------------------
// Balanced barrier-free flash attention (direct-global K/V).
// R1 post-mortem: removing barriers+staging was right (no more DMA lock-step)
// but splitting mt0/mt1 across waves made the BLOCK live as long as its
// longest wave (32-y iters) while half its waves idle after y+1 iters ->
// effective TLP decayed (Occupancy 32%, MfmaUtil 8.5%). Fix: restore R0's
// balanced pairing — each wave owns rows 64y+16w AND 64(31-y)+16w, loops
// kt=y..31 (33 MFMA-units/wave, identical across the whole grid, all waves
// retire together) — while keeping R1's direct-global fragment loads
// (contiguous 16B/lane; K/V tiles L1/L2-resident) and zero barriers.
// LDS = wave-local P only (16KB); __launch_bounds__(256,4) -> <=128 VGPR ->
// 16 waves/CU (2x the R0 kernel), no lock-step, balanced retirement.
// Math identical to R0 (fixed-max softmax, ones-MFMA l, row-2047 fixup).
// ---------------------------------------------------------------------------
__global__ __launch_bounds__(256, 4) void attn_dg(
    const unsigned short* __restrict__ qh, const unsigned short* __restrict__ kh,
    const unsigned short* __restrict__ vth, unsigned short* __restrict__ vals) {
  __shared__ unsigned short smP[4 * 32 * 64];  // 16KB: per-wave 32x64 P slice
  const int tid = threadIdx.x;
  const int lane = tid & 63;
  const int w = tid >> 6;
  const int l15 = lane & 15;
  const int quad = lane >> 4;
  const int bh = blockIdx.x;
  const int y = blockIdx.y;
  const int rbase[2] = {64 * y + 16 * w, 64 * (31 - y) + 16 * w};
  const int ktB = 31 - y;
  const bool fix = (y == 0) && (w == 3);  // owns row 2047; sees all keys
  const size_t base = (size_t)bh * (Ss * HDd);

  // Q fragments (Q pre-scaled by 0.125*log2e at gemm_qkv)
  bfrag Qh[2][2];
#pragma unroll
  for (int mt = 0; mt < 2; ++mt)
#pragma unroll
    for (int ks = 0; ks < 2; ++ks) {
      const size_t off = base + (size_t)(rbase[mt] + l15) * 64 + ks * 32 + quad * 8;
      Qh[mt][ks] = *(const bfrag*)(qh + off);
    }

  bfrag vone;
#pragma unroll
  for (int j = 0; j < 8; ++j) vone[j] = (short)0x3F80;  // bf16 1.0

  ffrag O[2][4], Oe[2], Vsum[4];
#pragma unroll
  for (int mt = 0; mt < 2; ++mt) {
#pragma unroll
    for (int dt = 0; dt < 4; ++dt) O[mt][dt] = (ffrag)0.f;
    Oe[mt] = (ffrag)0.f;
  }
#pragma unroll
  for (int dt = 0; dt < 4; ++dt) Vsum[dt] = (ffrag)0.f;

  for (int kt = y; kt < 32; ++kt) {
    const bool bact = (kt >= ktB);

    // ---- S = Q K^T — K fragments straight from global (batch loads first,
    // MFMAs after: compiler counts vmcnt down across the cluster)
    bfrag Kreg[4][2];
#pragma unroll
    for (int nt = 0; nt < 4; ++nt) {
      const int krow = kt * 64 + nt * 16 + l15;
#pragma unroll
      for (int ks = 0; ks < 2; ++ks)
        Kreg[nt][ks] =
            *(const bfrag*)(kh + base + (size_t)krow * 64 + ks * 32 + quad * 8);
    }
    ffrag S[2][4];
#pragma unroll
    for (int mt = 0; mt < 2; ++mt)
#pragma unroll
      for (int nt = 0; nt < 4; ++nt) S[mt][nt] = (ffrag)0.f;
#pragma unroll
    for (int nt = 0; nt < 4; ++nt)
#pragma unroll
      for (int ks = 0; ks < 2; ++ks) {
        S[0][nt] = __builtin_amdgcn_mfma_f32_16x16x32_bf16(Qh[0][ks], Kreg[nt][ks],
                                                           S[0][nt], 0, 0, 0);
        if (bact)
          S[1][nt] = __builtin_amdgcn_mfma_f32_16x16x32_bf16(Qh[1][ks], Kreg[nt][ks],
                                                             S[1][nt], 0, 0, 0);
      }

    // ---- V fragment loads issued here: exp2/cvt/P-write phase covers latency
    bfrag Vreg[2][4];
#pragma unroll
    for (int ks = 0; ks < 2; ++ks)
#pragma unroll
      for (int dt = 0; dt < 4; ++dt)
        Vreg[ks][dt] = *(const bfrag*)(vth + base + (size_t)(dt * 16 + l15) * 2048 +
                                       kt * 64 + ks * 32 + quad * 8);

    // ---- p = exp2(S [+ CM if masked]); packed bf16 cvt; store to P LDS
    const float CM = -1.442695041e9f;  // -1e9 * log2(e)
#pragma unroll
    for (int mt = 0; mt < 2; ++mt) {
      if (mt == 1 && !bact) continue;
      const bool partial = (kt == (mt == 0 ? y : ktB));
#pragma unroll
      for (int nt = 0; nt < 4; ++nt) {
        const int key = nt * 16 + l15;
#pragma unroll
        for (int rp = 0; rp < 2; ++rp) {
          float t0 = S[mt][nt][2 * rp];
          float t1 = S[mt][nt][2 * rp + 1];
          if (partial) {
            const int jg = kt * 64 + key;
            const int ig = rbase[mt] + quad * 4 + 2 * rp;
            if (jg <= ig) t0 += CM;
            if (jg <= ig + 1) t1 += CM;
          }
          float2 pf;
          pf.x = __builtin_amdgcn_exp2f(t0);
          pf.y = __builtin_amdgcn_exp2f(t1);
          const __hip_bfloat162 pb = __float22bfloat162_rn(pf);
          const unsigned short* pbs = (const unsigned short*)&pb;
          const int prow0 = w * 32 + mt * 16 + quad * 4 + 2 * rp;
          smP[prow0 * 64 + (((key >> 3) ^ (prow0 & 7)) * 8 + (key & 7))] = pbs[0];
          const int prow1 = prow0 + 1;
          smP[prow1 * 64 + (((key >> 3) ^ (prow1 & 7)) * 8 + (key & 7))] = pbs[1];
        }
      }
    }

    // ---- PV (V from regs) + l via ones-MFMA (+ Vsum on the fix wave)
#pragma unroll
    for (int ks = 0; ks < 2; ++ks) {
      bfrag pA[2];
#pragma unroll
      for (int mt = 0; mt < 2; ++mt) {
        if (mt == 1 && !bact) continue;
        const int prow = w * 32 + mt * 16 + l15;
        pA[mt] = *(const bfrag*)&smP[prow * 64 + ((ks * 4 + quad) ^ (prow & 7)) * 8];
      }
      Oe[0] = __builtin_amdgcn_mfma_f32_16x16x32_bf16(pA[0], vone, Oe[0], 0, 0, 0);
      if (bact)
        Oe[1] = __builtin_amdgcn_mfma_f32_16x16x32_bf16(pA[1], vone, Oe[1], 0, 0, 0);
#pragma unroll
      for (int dt = 0; dt < 4; ++dt) {
        O[0][dt] = __builtin_amdgcn_mfma_f32_16x16x32_bf16(pA[0], Vreg[ks][dt],
                                                           O[0][dt], 0, 0, 0);
        if (bact)
          O[1][dt] = __builtin_amdgcn_mfma_f32_16x16x32_bf16(pA[1], Vreg[ks][dt],
                                                             O[1][dt], 0, 0, 0);
        if (fix)
          Vsum[dt] = __builtin_amdgcn_mfma_f32_16x16x32_bf16(vone, Vreg[ks][dt],
                                                             Vsum[dt], 0, 0, 0);
      }
    }
  }

  // ---- epilogue: vals[b][s][h*64+d] single bf16; l = Oe row sum.
  // Row 2047 (fully masked -> exactly uniform) = mean(V), from Vsum.
  const int b = bh >> 4;
  const int h = bh & 15;
#pragma unroll
  for (int mt = 0; mt < 2; ++mt)
#pragma unroll
    for (int r = 0; r < 4; ++r) {
      const float inv = 1.0f / Oe[mt][r];
      const int s = rbase[mt] + quad * 4 + r;
      const size_t rowoff = ((size_t)b * 2048 + s) * 1024 + h * 64;
#pragma unroll
      for (int dt = 0; dt < 4; ++dt) {
        float val = O[mt][dt][r] * inv;
        if (fix && mt == 1 && quad == 3 && r == 3)  // s == 2047
          val = Vsum[dt][r] * (1.0f / 2048.0f);
        vals[rowoff + dt * 16 + l15] = f2bf(val);
      }
    }
}

// ---------------------------------------------------------------------------
// ws (64 MB): qh[0,8) kh[8,16) vth[16,24) vals[24,32)
// wqh[48,54) wql[54,60) woh[60,62) wol[62,64).
// d_out: xh[0,8) (dead after gemm_qkv); gemm_out2 writes final fp32 directly.
// ---------------------------------------------------------------------------
extern "C" void kernel_launch(void* const* d_in, const int* in_sizes, int n_in,
                              void* d_out, int out_size, void* d_ws, size_t ws_size,
                              hipStream_t stream) {
  const float* x    = (const float*)d_in[0];
  const float* Wqkv = (const float*)d_in[1];
  const float* bqkv = (const float*)d_in[2];
  const float* Wout = (const float*)d_in[3];
  const float* bout = (const float*)d_in[4];
  float* out = (float*)d_out;
  char* wsb = (char*)d_ws;

  unsigned short* qhp  = (unsigned short*)d_ws;
  unsigned short* khp  = qhp + 1 * 4194304;
  unsigned short* vthp = qhp + 2 * 4194304;
  unsigned short* vals = qhp + 3 * 4194304;
  unsigned short* wqh  = (unsigned short*)(wsb + (48u << 20));
  unsigned short* wql  = (unsigned short*)(wsb + (54u << 20));
  unsigned short* woh  = (unsigned short*)(wsb + (60u << 20));
  unsigned short* wol  = (unsigned short*)(wsb + (62u << 20));
  unsigned short* xh   = (unsigned short*)d_out;

  dim3 blk(256);
  split_all<<<8192, blk, 0, stream>>>(x, xh, Wqkv, wqh, wql, Wout, woh, wol);
  gemm_qkv<<<dim3(32, 24), blk, 0, stream>>>(xh, wqh, wql, bqkv, qhp, khp, vthp);
  attn_dg<<<dim3(32, 16), blk, 0, stream>>>(qhp, khp, vthp, vals);
  gemm_out2<<<dim3(32, 16), blk, 0, stream>>>(vals, woh, wol, bout, out);
}

// Round 3
// 202.754 us; speedup vs baseline: 2.0833x; 2.0833x over previous
//
#include <hip/hip_runtime.h>
#include <hip/hip_bf16.h>
#include <math.h>

#define Bb 2
#define Ss 2048
#define Ee 1024
#define Hh 16
#define HDd 64
#define NEG_INF_F -1000000000.0f

typedef __attribute__((ext_vector_type(8))) short bfrag;     // 8 bf16
typedef __attribute__((ext_vector_type(4))) float ffrag;     // 16x16 C/D
typedef __attribute__((ext_vector_type(16))) float ffrag16;  // 32x32 C/D
typedef __attribute__((ext_vector_type(8))) unsigned short us8;

#define C1F 0.1803368801f  /* 0.125 * log2(e) — folded into Q at gemm_qkv */

// ---- bf16 helpers ----------------------------------------------------------
__device__ __forceinline__ unsigned short f2bf(float x) {
  unsigned u = __float_as_uint(x);
  u += 0x7fffu + ((u >> 16) & 1u);
  return (unsigned short)(u >> 16);
}
__device__ __forceinline__ float bf2f(unsigned short h) {
  return __uint_as_float(((unsigned)h) << 16);
}

__device__ __forceinline__ void async_copy16(void* lds, const void* g) {
  __builtin_amdgcn_global_load_lds(
      (const __attribute__((address_space(1))) unsigned int*)g,
      (__attribute__((address_space(3))) unsigned int*)lds, 16, 0, 0);
}

// ---------------------------------------------------------------------------
// Fused split pass: x (4M) -> hi only; Wqkv (3M), Wout (1M) -> hi/lo.
// ---------------------------------------------------------------------------
__global__ __launch_bounds__(256) void split_all(
    const float* __restrict__ x, unsigned short* __restrict__ xh,
    const float* __restrict__ wq, unsigned short* __restrict__ wqh,
    unsigned short* __restrict__ wql,
    const float* __restrict__ wo, unsigned short* __restrict__ woh,
    unsigned short* __restrict__ wol) {
  int bid = blockIdx.x;
  const float* in;
  unsigned short *hi, *lo;
  if (bid < 4096) { in = x; hi = xh; lo = nullptr; }
  else if (bid < 7168) { bid -= 4096; in = wq; hi = wqh; lo = wql; }
  else { bid -= 7168; in = wo; hi = woh; lo = wol; }
  const int idx = (bid * 256 + threadIdx.x) * 4;
  const float4 v = *(const float4*)(in + idx);
  unsigned short h0 = f2bf(v.x), h1 = f2bf(v.y), h2 = f2bf(v.z), h3 = f2bf(v.w);
  ushort4 hv = {h0, h1, h2, h3};
  *(ushort4*)(hi + idx) = hv;
  if (lo) {
    ushort4 lv = {f2bf(v.x - bf2f(h0)), f2bf(v.y - bf2f(h1)),
                  f2bf(v.z - bf2f(h2)), f2bf(v.w - bf2f(h3))};
    *(ushort4*)(lo + idx) = lv;
  }
}

// ---------------------------------------------------------------------------
// LDS slot map (rows of 32 bf16 = 4 x 16B chunks):
// slot(row,q) = (row>>1)*8 + ((((row&1)*4)|q) ^ ((row>>1)&7)).
// ---------------------------------------------------------------------------
__device__ __forceinline__ int gemm_slot(int row, int q) {
  return (row >> 1) * 8 + ((((row & 1) * 4) | q) ^ ((row >> 1) & 7));
}
__device__ __forceinline__ int slot_src_off(int slot, int ld) {
  const int dr = slot >> 3;
  const int idx8 = (slot & 7) ^ (dr & 7);
  const int row = dr * 2 + (idx8 >> 2);
  const int q = idx8 & 3;
  return row * ld + q * 8;
}

// ---------------------------------------------------------------------------
// QKV GEMM, 32x32x16 core: C = xh * (Wh + Wl)^T + bias (2 MFMAs/product).
// 128x128 tile. Epilogue (all single bf16): Q pre-scaled by C1F -> [bh][s][64];
// K -> [bh][s][64]; V^T -> [bh][d][s].
// ---------------------------------------------------------------------------
__global__ __launch_bounds__(256) void gemm_qkv(
    const unsigned short* __restrict__ Ah,
    const unsigned short* __restrict__ Bh, const unsigned short* __restrict__ Bl,
    const float* __restrict__ bias,
    unsigned short* __restrict__ q_h, unsigned short* __restrict__ k_h,
    unsigned short* __restrict__ vt_h) {
  __shared__ unsigned short sm[3 * 4096];
  const int tid = threadIdx.x;
  const int lane = tid & 63;
  const int w = tid >> 6;
  const int wm = w >> 1;
  const int wn = w & 1;
  const int l31 = lane & 31;
  const int e = lane >> 5;
  const int m0 = blockIdx.x * 128;
  const int n0 = blockIdx.y * 128;

  int coff[2], ldsb[2];
#pragma unroll
  for (int u = 0; u < 2; ++u) {
    const int slot = w * 128 + u * 64 + lane;
    coff[u] = slot_src_off(slot, 1024);
    ldsb[u] = (w * 128 + u * 64) * 8;
  }
  const unsigned short* srcs[3] = {
      Ah + (size_t)m0 * 1024, Bh + (size_t)n0 * 1024, Bl + (size_t)n0 * 1024};

  ffrag16 acc[2][2];
#pragma unroll
  for (int i = 0; i < 2; ++i)
#pragma unroll
    for (int j = 0; j < 2; ++j) acc[i][j] = (ffrag16)0.f;

  int ca[2][2], cb[2][2];
#pragma unroll
  for (int t = 0; t < 2; ++t)
#pragma unroll
    for (int h2 = 0; h2 < 2; ++h2) {
      ca[t][h2] = gemm_slot(wm * 64 + t * 32 + l31, h2 * 2 + e) * 8;
      cb[t][h2] = gemm_slot(wn * 64 + t * 32 + l31, h2 * 2 + e) * 8;
    }

  for (int k0 = 0; k0 < 1024; k0 += 32) {
    __syncthreads();
#pragma unroll
    for (int t = 0; t < 3; ++t)
#pragma unroll
      for (int u = 0; u < 2; ++u)
        async_copy16(&sm[t * 4096 + ldsb[u]], srcs[t] + coff[u] + k0);
    __syncthreads();

    bfrag ah[2][2], bhf[2][2], blf[2][2];
#pragma unroll
    for (int t = 0; t < 2; ++t)
#pragma unroll
      for (int h2 = 0; h2 < 2; ++h2) {
        ah[t][h2] = *(const bfrag*)&sm[0 * 4096 + ca[t][h2]];
        bhf[t][h2] = *(const bfrag*)&sm[1 * 4096 + cb[t][h2]];
        blf[t][h2] = *(const bfrag*)&sm[2 * 4096 + cb[t][h2]];
      }
#pragma unroll
    for (int mt = 0; mt < 2; ++mt)
#pragma unroll
      for (int nt = 0; nt < 2; ++nt)
#pragma unroll
        for (int h2 = 0; h2 < 2; ++h2) {
          acc[mt][nt] = __builtin_amdgcn_mfma_f32_32x32x16_bf16(
              ah[mt][h2], bhf[nt][h2], acc[mt][nt], 0, 0, 0);
          acc[mt][nt] = __builtin_amdgcn_mfma_f32_32x32x16_bf16(
              ah[mt][h2], blf[nt][h2], acc[mt][nt], 0, 0, 0);
        }
  }

#pragma unroll
  for (int nt = 0; nt < 2; ++nt) {
    const int n = n0 + wn * 64 + nt * 32 + l31;
    const float bv = bias[n];
    const int h = n / 192;
    const int c = n - h * 192;
    const int d = c & 63;
#pragma unroll
    for (int mt = 0; mt < 2; ++mt) {
      if (c >= 128) {
#pragma unroll
        for (int g = 0; g < 4; ++g) {
          const int m = m0 + wm * 64 + mt * 32 + g * 8 + e * 4;
          const int bidx = m >> 11;
          const int s = m & 2047;
          ushort4 hv4;
          unsigned short* ph = (unsigned short*)&hv4;
#pragma unroll
          for (int r = 0; r < 4; ++r)
            ph[r] = f2bf(acc[mt][nt][g * 4 + r] + bv);
          const size_t off =
              (size_t)(bidx * 16 + h) * (64 * 2048) + (size_t)d * 2048 + s;
          *(ushort4*)(vt_h + off) = hv4;
        }
      } else {
        const float scale = (c < 64) ? C1F : 1.0f;
        unsigned short* dh = (c < 64) ? q_h : k_h;
#pragma unroll
        for (int g = 0; g < 4; ++g)
#pragma unroll
          for (int r = 0; r < 4; ++r) {
            const int m = m0 + wm * 64 + mt * 32 + g * 8 + e * 4 + r;
            const int bidx = m >> 11;
            const int s = m & 2047;
            const size_t off =
                (size_t)(bidx * 16 + h) * (2048 * 64) + (size_t)s * 64 + d;
            dh[off] = f2bf((acc[mt][nt][g * 4 + r] + bv) * scale);
          }
      }
    }
  }
}

// ---------------------------------------------------------------------------
// Out-proj GEMM: A = vals single bf16, B = Wout hi/lo (2 MFMAs/product).
// 128x64 tile, 512 blocks. Writes fp32+bias directly to out.
// ---------------------------------------------------------------------------
__global__ __launch_bounds__(256) void gemm_out2(
    const unsigned short* __restrict__ A,
    const unsigned short* __restrict__ Bh, const unsigned short* __restrict__ Bl,
    const float* __restrict__ bias, float* __restrict__ out) {
  __shared__ unsigned short sm[8192];
  const int tid = threadIdx.x;
  const int lane = tid & 63;
  const int w = tid >> 6;
  const int wm = w >> 1;
  const int wn = w & 1;
  const int l31 = lane & 31;
  const int e = lane >> 5;
  const int m0 = blockIdx.x * 128;
  const int n0 = blockIdx.y * 64;

  int acoff[2], aldsb[2];
#pragma unroll
  for (int u = 0; u < 2; ++u) {
    const int slot = w * 128 + u * 64 + lane;
    acoff[u] = slot_src_off(slot, 1024);
    aldsb[u] = (w * 128 + u * 64) * 8;
  }
  const int bslot = w * 64 + lane;
  const int bcoff = slot_src_off(bslot, 1024);
  const int bldsb = bslot * 8;

  const unsigned short* Ap  = A + (size_t)m0 * 1024;
  const unsigned short* Bph = Bh + (size_t)n0 * 1024;
  const unsigned short* Bpl = Bl + (size_t)n0 * 1024;

  ffrag16 acc[2];
  acc[0] = (ffrag16)0.f;
  acc[1] = (ffrag16)0.f;

  int ca[2][2], cb[2];
#pragma unroll
  for (int t = 0; t < 2; ++t)
#pragma unroll
    for (int h2 = 0; h2 < 2; ++h2)
      ca[t][h2] = gemm_slot(wm * 64 + t * 32 + l31, h2 * 2 + e) * 8;
#pragma unroll
  for (int h2 = 0; h2 < 2; ++h2)
    cb[h2] = gemm_slot(wn * 32 + l31, h2 * 2 + e) * 8;

  for (int k0 = 0; k0 < 1024; k0 += 32) {
    __syncthreads();
#pragma unroll
    for (int u = 0; u < 2; ++u)
      async_copy16(&sm[0 + aldsb[u]], Ap + acoff[u] + k0);
    async_copy16(&sm[4096 + bldsb], Bph + bcoff + k0);
    async_copy16(&sm[6144 + bldsb], Bpl + bcoff + k0);
    __syncthreads();

    bfrag ah[2][2], bhf[2], blf[2];
#pragma unroll
    for (int t = 0; t < 2; ++t)
#pragma unroll
      for (int h2 = 0; h2 < 2; ++h2)
        ah[t][h2] = *(const bfrag*)&sm[0 + ca[t][h2]];
#pragma unroll
    for (int h2 = 0; h2 < 2; ++h2) {
      bhf[h2] = *(const bfrag*)&sm[4096 + cb[h2]];
      blf[h2] = *(const bfrag*)&sm[6144 + cb[h2]];
    }
#pragma unroll
    for (int mt = 0; mt < 2; ++mt)
#pragma unroll
      for (int h2 = 0; h2 < 2; ++h2) {
        acc[mt] = __builtin_amdgcn_mfma_f32_32x32x16_bf16(
            ah[mt][h2], bhf[h2], acc[mt], 0, 0, 0);
        acc[mt] = __builtin_amdgcn_mfma_f32_32x32x16_bf16(
            ah[mt][h2], blf[h2], acc[mt], 0, 0, 0);
      }
  }

  const int n = n0 + wn * 32 + l31;
  const float bv = bias[n];
#pragma unroll
  for (int mt = 0; mt < 2; ++mt)
#pragma unroll
    for (int g = 0; g < 4; ++g)
#pragma unroll
      for (int r = 0; r < 4; ++r) {
        const int m = m0 + wm * 64 + mt * 32 + g * 8 + e * 4 + r;
        out[(size_t)m * 1024 + n] = acc[mt][g * 4 + r] + bv;
      }
}

// ---------------------------------------------------------------------------
// Two-phase balanced flash attention, double-buffered LDS staging.
// R2 post-mortem: batched Kreg/Vreg arrays + dual-mt state overflowed the
// (256,4) cap -> scratch spill (WRITE_SIZE 194MB). R0's remaining costs:
// 64KB LDS -> 2 blocks/CU, and block span 32-y iters (17..32) -> ~20-25%
// CU-idle tail. Fix both, keeping R0's proven staged-LDS math:
//  - each block runs TWO sequential 64-row phases: row-block y (span 32-y)
//    then row-block 31-y (span y+1) -> uniform 33-iter span for every block;
//  - single-mt per phase -> S[4]+O[4]+Oe+Q state ~ 100 VGPR, no spill;
//  - double-buffered 16KB K+V stages + 8KB P = 40KB LDS -> 4 blocks/CU
//    (16 waves/CU, 2x R0); __syncthreads per iter (vmcnt(0)+barrier),
//    prefetch distance 1 — K/V are L2/L3-resident (R1: FETCH=compulsory),
//    and 4 resident blocks/CU cover the shorter prefetch window.
// Row 2047: (y=0,w=3) wave sees all 32 V tiles in phase A (Vsum ones-MFMA)
// and owns row 2047 in phase B -> same-wave fixup, no cross-wave skip.
// ---------------------------------------------------------------------------
__global__ __launch_bounds__(256, 4) void attn_2ph(
    const unsigned short* __restrict__ qh, const unsigned short* __restrict__ kh,
    const unsigned short* __restrict__ vth, unsigned short* __restrict__ vals) {
  __shared__ unsigned short sm[2 * 8192 + 4096];  // 2 stage sets (K+V) + P = 40KB
  const int tid = threadIdx.x;
  const int lane = tid & 63;
  const int w = tid >> 6;
  const int l15 = lane & 15;
  const int quad = lane >> 4;
  const int bh = blockIdx.x;
  const int y = blockIdx.y;
  const size_t base = (size_t)bh * (Ss * HDd);
  const int b = bh >> 4;
  const int h = bh & 15;
  const int PB = 16384;  // P region base (shorts)

  // staging offsets (same swizzled slot map as R0)
  const int c0 = w * 128 + lane;
  const int c1 = c0 + 64;
  const int r0 = c0 >> 3, r1 = c1 >> 3;
  const int s0 = ((c0 & 7) ^ (r0 & 7)) * 8;
  const int s1 = ((c1 & 7) ^ (r1 & 7)) * 8;
  const int koff0 = r0 * 64 + s0, koff1 = r1 * 64 + s1;
  const int voff0 = r0 * 2048 + s0, voff1 = r1 * 2048 + s1;
  const int ldsc0 = c0 * 8;
  const int ldsc1 = c1 * 8;

  bfrag vone;
#pragma unroll
  for (int j = 0; j < 8; ++j) vone[j] = (short)0x3F80;  // bf16 1.0

  const bool fixw = (y == 0) && (w == 3);  // phase A sees all kt; phase B owns row 2047
  ffrag Vsum[4];
#pragma unroll
  for (int dt = 0; dt < 4; ++dt) Vsum[dt] = (ffrag)0.f;

  for (int ph = 0; ph < 2; ++ph) {
    const int ybk = ph ? (31 - y) : y;
    const int rb = 64 * ybk + 16 * w;  // this wave's 16 query rows

    // Q fragments (Q pre-scaled by 0.125*log2e at gemm_qkv)
    bfrag Qf[2];
#pragma unroll
    for (int ks = 0; ks < 2; ++ks)
      Qf[ks] = *(const bfrag*)(qh + base + (size_t)(rb + l15) * 64 + ks * 32 + quad * 8);

    ffrag O[4], Oe;
#pragma unroll
    for (int dt = 0; dt < 4; ++dt) O[dt] = (ffrag)0.f;
    Oe = (ffrag)0.f;

    int cur = 0, nxt = 8192;  // short offsets of the two stage sets
    {  // prologue: stage tile ybk into cur
      const unsigned short* kp = kh + base + ybk * 4096;
      const unsigned short* vp = vth + base + ybk * 64;
      async_copy16(&sm[cur + ldsc0], kp + koff0);
      async_copy16(&sm[cur + ldsc1], kp + koff1);
      async_copy16(&sm[cur + 4096 + ldsc0], vp + voff0);
      async_copy16(&sm[cur + 4096 + ldsc1], vp + voff1);
    }

    for (int kt = ybk; kt < 32; ++kt) {
      __syncthreads();  // drains own DMA (vmcnt 0) + seals nxt for overwrite
      if (kt + 1 < 32) {  // prefetch next tile into nxt (covered by compute)
        const unsigned short* kp = kh + base + (kt + 1) * 4096;
        const unsigned short* vp = vth + base + (kt + 1) * 64;
        async_copy16(&sm[nxt + ldsc0], kp + koff0);
        async_copy16(&sm[nxt + ldsc1], kp + koff1);
        async_copy16(&sm[nxt + 4096 + ldsc0], vp + voff0);
        async_copy16(&sm[nxt + 4096 + ldsc1], vp + voff1);
      }

      // ---- S = Q K^T (Q pre-scaled; K single bf16 from LDS)
      ffrag S[4];
#pragma unroll
      for (int nt = 0; nt < 4; ++nt) S[nt] = (ffrag)0.f;
#pragma unroll
      for (int nt = 0; nt < 4; ++nt) {
        const int krow = nt * 16 + l15;
#pragma unroll
        for (int ks = 0; ks < 2; ++ks) {
          const bfrag kbh =
              *(const bfrag*)&sm[cur + krow * 64 + ((ks * 4 + quad) ^ (krow & 7)) * 8];
          S[nt] = __builtin_amdgcn_mfma_f32_16x16x32_bf16(Qf[ks], kbh, S[nt], 0, 0, 0);
        }
      }

      // ---- p = exp2(S [+ CM if masked]); packed bf16 cvt; store to P LDS
      const float CM = -1.442695041e9f;  // -1e9 * log2(e)
      const bool partial = (kt == ybk);
#pragma unroll
      for (int nt = 0; nt < 4; ++nt) {
        const int key = nt * 16 + l15;
#pragma unroll
        for (int rp = 0; rp < 2; ++rp) {
          float t0 = S[nt][2 * rp];
          float t1 = S[nt][2 * rp + 1];
          if (partial) {
            const int jg = kt * 64 + key;
            const int ig = rb + quad * 4 + 2 * rp;
            if (jg <= ig) t0 += CM;
            if (jg <= ig + 1) t1 += CM;
          }
          float2 pf;
          pf.x = __builtin_amdgcn_exp2f(t0);
          pf.y = __builtin_amdgcn_exp2f(t1);
          const __hip_bfloat162 pb = __float22bfloat162_rn(pf);
          const unsigned short* pbs = (const unsigned short*)&pb;
          const int pr0 = w * 16 + quad * 4 + 2 * rp;
          sm[PB + pr0 * 64 + (((key >> 3) ^ (pr0 & 7)) * 8 + (key & 7))] = pbs[0];
          const int pr1 = pr0 + 1;
          sm[PB + pr1 * 64 + (((key >> 3) ^ (pr1 & 7)) * 8 + (key & 7))] = pbs[1];
        }
      }

      // ---- PV (V single bf16 from LDS) + l via ones-MFMA (+ Vsum, fix wave)
#pragma unroll
      for (int ks = 0; ks < 2; ++ks) {
        const int prow = w * 16 + l15;
        const bfrag pA =
            *(const bfrag*)&sm[PB + prow * 64 + ((ks * 4 + quad) ^ (prow & 7)) * 8];
        Oe = __builtin_amdgcn_mfma_f32_16x16x32_bf16(pA, vone, Oe, 0, 0, 0);
#pragma unroll
        for (int dt = 0; dt < 4; ++dt) {
          const int vrow = dt * 16 + l15;
          const bfrag vbh =
              *(const bfrag*)&sm[cur + 4096 + vrow * 64 + ((ks * 4 + quad) ^ (vrow & 7)) * 8];
          O[dt] = __builtin_amdgcn_mfma_f32_16x16x32_bf16(pA, vbh, O[dt], 0, 0, 0);
          if (fixw && ph == 0)
            Vsum[dt] = __builtin_amdgcn_mfma_f32_16x16x32_bf16(vone, vbh, Vsum[dt], 0, 0, 0);
        }
      }
      const int t = cur; cur = nxt; nxt = t;  // swap stage sets
    }

    // ---- epilogue: vals[b][s][h*64+d] single bf16; l = Oe row sum.
    // Row 2047 (fully masked -> exactly uniform) = mean(V), from Vsum (phase B).
#pragma unroll
    for (int r = 0; r < 4; ++r) {
      const float inv = 1.0f / Oe[r];
      const int s = rb + quad * 4 + r;
      const size_t rowoff = ((size_t)b * 2048 + s) * 1024 + h * 64;
#pragma unroll
      for (int dt = 0; dt < 4; ++dt) {
        float val = O[dt][r] * inv;
        if (fixw && ph == 1 && quad == 3 && r == 3)  // s == 2047
          val = Vsum[dt][3] * (1.0f / 2048.0f);
        vals[rowoff + dt * 16 + l15] = f2bf(val);
      }
    }
    __syncthreads();  // seal all stage reads before next phase's prologue DMA
  }
}

// ---------------------------------------------------------------------------
// ws (64 MB): qh[0,8) kh[8,16) vth[16,24) vals[24,32)
// wqh[48,54) wql[54,60) woh[60,62) wol[62,64).
// d_out: xh[0,8) (dead after gemm_qkv); gemm_out2 writes final fp32 directly.
// ---------------------------------------------------------------------------
extern "C" void kernel_launch(void* const* d_in, const int* in_sizes, int n_in,
                              void* d_out, int out_size, void* d_ws, size_t ws_size,
                              hipStream_t stream) {
  const float* x    = (const float*)d_in[0];
  const float* Wqkv = (const float*)d_in[1];
  const float* bqkv = (const float*)d_in[2];
  const float* Wout = (const float*)d_in[3];
  const float* bout = (const float*)d_in[4];
  float* out = (float*)d_out;
  char* wsb = (char*)d_ws;

  unsigned short* qhp  = (unsigned short*)d_ws;
  unsigned short* khp  = qhp + 1 * 4194304;
  unsigned short* vthp = qhp + 2 * 4194304;
  unsigned short* vals = qhp + 3 * 4194304;
  unsigned short* wqh  = (unsigned short*)(wsb + (48u << 20));
  unsigned short* wql  = (unsigned short*)(wsb + (54u << 20));
  unsigned short* woh  = (unsigned short*)(wsb + (60u << 20));
  unsigned short* wol  = (unsigned short*)(wsb + (62u << 20));
  unsigned short* xh   = (unsigned short*)d_out;

  dim3 blk(256);
  split_all<<<8192, blk, 0, stream>>>(x, xh, Wqkv, wqh, wql, Wout, woh, wol);
  gemm_qkv<<<dim3(32, 24), blk, 0, stream>>>(xh, wqh, wql, bqkv, qhp, khp, vthp);
  attn_2ph<<<dim3(32, 16), blk, 0, stream>>>(qhp, khp, vthp, vals);
  gemm_out2<<<dim3(32, 16), blk, 0, stream>>>(vals, woh, wol, bout, out);
}